// Round 1
// baseline (3196.807 us; speedup 1.0000x reference)
//
#include <hip/hip_runtime.h>
#include <hip/hip_bf16.h>
#include <math.h>

// Shapes (compile-time)
#define N_TOT 16384   // B*T
#define AG 8          // agents
#define OBSD 256
#define SD 512
#define NACT 32
#define ED 64
#define NH 4
#define HD 16
#define HYP 256
#define NB 16         // rows of n per mixer block

// ---------------------------------------------------------------------------
// Kernel 1: per-agent encoders + multihead self-attention -> attended_qs[N,AG]
// One block per n, 256 threads. All intermediates in LDS.
// ---------------------------------------------------------------------------
__global__ __launch_bounds__(256) void k_enc_attn(
    const float* __restrict__ agent_qs,
    const float* __restrict__ observations,
    const int*   __restrict__ actions,
    const float* __restrict__ W_obs, const float* __restrict__ b_obs,
    const float* __restrict__ W_act, const float* __restrict__ b_act,
    const float* __restrict__ W_q,   const float* __restrict__ b_q,
    const float* __restrict__ Wqkv,  const float* __restrict__ bqkv,
    const float* __restrict__ Wo,    const float* __restrict__ bo,
    const float* __restrict__ Wa2q,  const float* __restrict__ ba2q,
    float* __restrict__ attended)
{
    __shared__ __align__(16) float s_obs[AG][OBSD];   // 8 KB
    __shared__ __align__(16) float s_x[AG][ED];       // 2 KB
    __shared__ __align__(16) float s_qkv[AG][3*ED];   // 6 KB
    __shared__ float s_p[NH][AG][AG];                 // 1 KB
    __shared__ __align__(16) float s_o[AG][ED];       // 2 KB

    const int n = blockIdx.x;
    const int t = threadIdx.x;

    // stage observations for this n
    {
        const float4* g = (const float4*)(observations + (size_t)n * (AG*OBSD));
        float4* s4 = (float4*)&s_obs[0][0];
        #pragma unroll
        for (int i = 0; i < (AG*OBSD/4)/256; ++i) s4[t + i*256] = g[t + i*256];
    }
    __syncthreads();

    // x[a][e] = obs_e + act_e + q_e
    {
        const int e  = t & (ED-1);
        const int a0 = t >> 6;            // 0..3
        const float wq    = W_q[e];
        const float bias0 = b_obs[e] + b_act[e] + b_q[e];
        const float* wrow = W_obs + e*OBSD;
        #pragma unroll
        for (int g = 0; g < 2; ++g) {
            const int a = a0 + g*4;
            float acc = 0.f;
            #pragma unroll 8
            for (int k = 0; k < OBSD; k += 4) {
                const float4 w = *(const float4*)(wrow + k);
                acc += w.x*s_obs[a][k] + w.y*s_obs[a][k+1]
                     + w.z*s_obs[a][k+2] + w.w*s_obs[a][k+3];
            }
            const int   act = actions[n*AG + a];
            const float qv  = agent_qs[n*AG + a];
            s_x[a][e] = acc + bias0 + W_act[e*NACT + act] + qv*wq;
        }
    }
    __syncthreads();

    // qkv = x @ Wqkv.T + bqkv   (1536 outputs, 6 per thread)
    #pragma unroll
    for (int g = 0; g < (AG*3*ED)/256; ++g) {
        const int i = t + g*256;
        const int a = i / (3*ED);
        const int j = i - a*(3*ED);
        const float* wrow = Wqkv + j*ED;
        float acc = bqkv[j];
        #pragma unroll
        for (int k = 0; k < ED; k += 4) {
            const float4 w = *(const float4*)(wrow + k);
            acc += w.x*s_x[a][k] + w.y*s_x[a][k+1]
                 + w.z*s_x[a][k+2] + w.w*s_x[a][k+3];
        }
        s_qkv[a][j] = acc;
    }
    __syncthreads();

    // scores: one (h,a,b) per thread
    {
        const int h = t >> 6, a = (t >> 3) & 7, b = t & 7;
        float acc = 0.f;
        #pragma unroll
        for (int d = 0; d < HD; ++d)
            acc += s_qkv[a][h*HD + d] * s_qkv[b][ED + h*HD + d];
        s_p[h][a][b] = acc * 0.25f;   // 1/sqrt(16)
    }
    __syncthreads();

    // softmax over b (32 rows)
    if (t < 32) {
        const int h = t >> 3, a = t & 7;
        float m = -1e30f;
        #pragma unroll
        for (int b = 0; b < AG; ++b) m = fmaxf(m, s_p[h][a][b]);
        float ex[AG]; float sum = 0.f;
        #pragma unroll
        for (int b = 0; b < AG; ++b) { ex[b] = __expf(s_p[h][a][b] - m); sum += ex[b]; }
        const float inv = 1.f / sum;
        #pragma unroll
        for (int b = 0; b < AG; ++b) s_p[h][a][b] = ex[b] * inv;
    }
    __syncthreads();

    // o = attn @ v (concat heads): 512 outputs, 2 per thread
    #pragma unroll
    for (int g = 0; g < (AG*ED)/256; ++g) {
        const int i = t + g*256;
        const int a = i >> 6, c = i & 63, h = c >> 4;
        float acc = 0.f;
        #pragma unroll
        for (int b = 0; b < AG; ++b) acc += s_p[h][a][b] * s_qkv[b][2*ED + c];
        s_o[a][c] = acc;
    }
    __syncthreads();

    // o-projection, pre-scaled by Wa2q (fuses the Linear(E,1))
    #pragma unroll
    for (int g = 0; g < (AG*ED)/256; ++g) {
        const int i = t + g*256;
        const int a = i >> 6, e2 = i & 63;
        const float* wrow = Wo + e2*ED;
        float acc = bo[e2];
        #pragma unroll
        for (int k = 0; k < ED; k += 4) {
            const float4 w = *(const float4*)(wrow + k);
            acc += w.x*s_o[a][k] + w.y*s_o[a][k+1]
                 + w.z*s_o[a][k+2] + w.w*s_o[a][k+3];
        }
        s_x[a][e2] = acc * Wa2q[e2];
    }
    __syncthreads();

    // attended[a] = sum_e + ba2q
    if (t < AG) {
        float s = ba2q[0];
        #pragma unroll
        for (int e2 = 0; e2 < ED; ++e2) s += s_x[t][e2];
        attended[n*AG + t] = s;
    }
}

// ---------------------------------------------------------------------------
// Kernel 2: QMIX hypernet mixing. NB=16 rows per block, 256 threads.
// st tile in LDS; weight rows streamed from global (L2-resident).
// ---------------------------------------------------------------------------
__global__ __launch_bounds__(256) void k_mixer(
    const float* __restrict__ states,
    const float* __restrict__ attended,
    const float* __restrict__ Wh1a, const float* __restrict__ bh1a,
    const float* __restrict__ Wh1b, const float* __restrict__ bh1b,
    const float* __restrict__ Whfa, const float* __restrict__ bhfa,
    const float* __restrict__ Whfb, const float* __restrict__ bhfb,
    const float* __restrict__ Wb1,  const float* __restrict__ bb1,
    const float* __restrict__ Wv1,  const float* __restrict__ bv1,
    const float* __restrict__ Wv2,  const float* __restrict__ bv2,
    float* __restrict__ out)
{
    __shared__ __align__(16) float s_st[NB][SD];    // 32 KB (live whole kernel)
    __shared__ __align__(16) float s_h[NB][HYP];    // 16 KB (h1a, then hfa)
    __shared__ __align__(16) float s_hid[NB][ED];   // 4 KB  (b1 + einsum acc -> elu input)
    __shared__ __align__(16) float s_prod[NB][ED];  // 4 KB
    __shared__ __align__(16) float s_v[NB][ED];     // 4 KB
    __shared__ float s_aq[NB][AG];                  // 0.5 KB

    const int n0 = blockIdx.x * NB;
    const int t  = threadIdx.x;

    // stage st tile + attended_qs
    {
        const float4* g = (const float4*)(states + (size_t)n0 * SD);
        float4* s4 = (float4*)&s_st[0][0];
        #pragma unroll
        for (int i = 0; i < (NB*SD/4)/256; ++i) s4[t + i*256] = g[t + i*256];
        if (t < NB*AG) ((float*)s_aq)[t] = attended[n0*AG + t];
    }
    __syncthreads();

    // h1a[n][t] = relu(st[n] . Wh1a[t] + bh1a[t])   (one j per thread, 16 n acc)
    {
        const float* wrow = Wh1a + t*SD;
        float acc[NB];
        #pragma unroll
        for (int n = 0; n < NB; ++n) acc[n] = 0.f;
        for (int k = 0; k < SD; k += 4) {
            const float4 w = *(const float4*)(wrow + k);
            #pragma unroll
            for (int n = 0; n < NB; ++n) {
                const float4 x = *(const float4*)(&s_st[n][k]);
                acc[n] += w.x*x.x + w.y*x.y + w.z*x.z + w.w*x.w;
            }
        }
        const float bb = bh1a[t];
        #pragma unroll
        for (int n = 0; n < NB; ++n) s_h[n][t] = fmaxf(acc[n] + bb, 0.f);
    }
    // b1 into s_hid (reads only s_st; no one reads s_hid until next barrier)
    #pragma unroll
    for (int g = 0; g < (NB*ED)/256; ++g) {
        const int i = t + g*256;
        const int n = i >> 6, e = i & 63;
        const float* wrow = Wb1 + e*SD;
        float acc = bb1[e];
        #pragma unroll 4
        for (int k = 0; k < SD; k += 4) {
            const float4 w = *(const float4*)(wrow + k);
            const float4 x = *(const float4*)(&s_st[n][k]);
            acc += w.x*x.x + w.y*x.y + w.z*x.z + w.w*x.w;
        }
        s_hid[n][e] = acc;
    }
    __syncthreads();

    // w1 = |h1a @ Wh1b.T + bh1b| ; hidden += aq[a] * w1[a][e]  (LDS atomics)
    #pragma unroll
    for (int g = 0; g < 2; ++g) {
        const int j = t + g*256;                 // 0..511 = a*64+e
        const float* wrow = Wh1b + j*HYP;
        float acc[NB];
        #pragma unroll
        for (int n = 0; n < NB; ++n) acc[n] = 0.f;
        for (int k = 0; k < HYP; k += 4) {
            const float4 w = *(const float4*)(wrow + k);
            #pragma unroll
            for (int n = 0; n < NB; ++n) {
                const float4 x = *(const float4*)(&s_h[n][k]);
                acc[n] += w.x*x.x + w.y*x.y + w.z*x.z + w.w*x.w;
            }
        }
        const float bb = bh1b[j];
        const int a = j >> 6, e = j & 63;
        #pragma unroll
        for (int n = 0; n < NB; ++n)
            atomicAdd(&s_hid[n][e], s_aq[n][a] * fabsf(acc[n] + bb));
    }
    __syncthreads();

    // hfa[n][t] = relu(st[n] . Whfa[t] + bhfa[t])  (overwrites s_h)
    {
        const float* wrow = Whfa + t*SD;
        float acc[NB];
        #pragma unroll
        for (int n = 0; n < NB; ++n) acc[n] = 0.f;
        for (int k = 0; k < SD; k += 4) {
            const float4 w = *(const float4*)(wrow + k);
            #pragma unroll
            for (int n = 0; n < NB; ++n) {
                const float4 x = *(const float4*)(&s_st[n][k]);
                acc[n] += w.x*x.x + w.y*x.y + w.z*x.z + w.w*x.w;
            }
        }
        const float bb = bhfa[t];
        #pragma unroll
        for (int n = 0; n < NB; ++n) s_h[n][t] = fmaxf(acc[n] + bb, 0.f);
    }
    __syncthreads();

    // w_f * elu(hidden)  and  v-branch
    #pragma unroll
    for (int g = 0; g < (NB*ED)/256; ++g) {
        const int i = t + g*256;
        const int n = i >> 6, e = i & 63;
        {   // w_f[n][e] = |hfa[n] . Whfb[e] + bhfb[e]|
            const float* wrow = Whfb + e*HYP;
            float acc = bhfb[e];
            #pragma unroll 4
            for (int k = 0; k < HYP; k += 4) {
                const float4 w = *(const float4*)(wrow + k);
                const float4 x = *(const float4*)(&s_h[n][k]);
                acc += w.x*x.x + w.y*x.y + w.z*x.z + w.w*x.w;
            }
            float h = s_hid[n][e];
            h = (h > 0.f) ? h : expm1f(h);       // elu
            s_prod[n][e] = fabsf(acc) * h;
        }
        {   // v1 branch: relu(st . Wv1[e] + bv1[e]) * Wv2[e]
            const float* wrow = Wv1 + e*SD;
            float acc = bv1[e];
            #pragma unroll 4
            for (int k = 0; k < SD; k += 4) {
                const float4 w = *(const float4*)(wrow + k);
                const float4 x = *(const float4*)(&s_st[n][k]);
                acc += w.x*x.x + w.y*x.y + w.z*x.z + w.w*x.w;
            }
            s_v[n][e] = fmaxf(acc, 0.f) * Wv2[e];
        }
    }
    __syncthreads();

    if (t < NB) {
        float y = bv2[0];
        #pragma unroll
        for (int e = 0; e < ED; ++e) y += s_prod[t][e] + s_v[t][e];
        out[n0 + t] = y;
    }
}

// ---------------------------------------------------------------------------
extern "C" void kernel_launch(void* const* d_in, const int* in_sizes, int n_in,
                              void* d_out, int out_size, void* d_ws, size_t ws_size,
                              hipStream_t stream) {
    const float* agent_qs     = (const float*)d_in[0];
    const float* states       = (const float*)d_in[1];
    const float* observations = (const float*)d_in[2];
    const int*   actions      = (const int*)  d_in[3];
    const float* W_obs = (const float*)d_in[4];  const float* b_obs = (const float*)d_in[5];
    const float* W_act = (const float*)d_in[6];  const float* b_act = (const float*)d_in[7];
    const float* W_q   = (const float*)d_in[8];  const float* b_q   = (const float*)d_in[9];
    const float* Wqkv  = (const float*)d_in[10]; const float* bqkv  = (const float*)d_in[11];
    const float* Wo    = (const float*)d_in[12]; const float* bo    = (const float*)d_in[13];
    const float* Wa2q  = (const float*)d_in[14]; const float* ba2q  = (const float*)d_in[15];
    const float* Wh1a  = (const float*)d_in[16]; const float* bh1a  = (const float*)d_in[17];
    const float* Wh1b  = (const float*)d_in[18]; const float* bh1b  = (const float*)d_in[19];
    const float* Whfa  = (const float*)d_in[20]; const float* bhfa  = (const float*)d_in[21];
    const float* Whfb  = (const float*)d_in[22]; const float* bhfb  = (const float*)d_in[23];
    const float* Wb1   = (const float*)d_in[24]; const float* bb1   = (const float*)d_in[25];
    const float* Wv1   = (const float*)d_in[26]; const float* bv1   = (const float*)d_in[27];
    const float* Wv2   = (const float*)d_in[28]; const float* bv2   = (const float*)d_in[29];

    float* attended = (float*)d_ws;          // [N_TOT, AG] fp32 = 512 KB
    float* out      = (float*)d_out;         // [N_TOT] fp32

    k_enc_attn<<<N_TOT, 256, 0, stream>>>(
        agent_qs, observations, actions,
        W_obs, b_obs, W_act, b_act, W_q, b_q,
        Wqkv, bqkv, Wo, bo, Wa2q, ba2q, attended);

    k_mixer<<<N_TOT/NB, 256, 0, stream>>>(
        states, attended,
        Wh1a, bh1a, Wh1b, bh1b, Whfa, bhfa, Whfb, bhfb,
        Wb1, bb1, Wv1, bv1, Wv2, bv2, out);
}

// Round 2
// 442.482 us; speedup vs baseline: 7.2247x; 7.2247x over previous
//
#include <hip/hip_runtime.h>
#include <hip/hip_bf16.h>
#include <math.h>

// Shapes (compile-time)
#define N_TOT 16384   // B*T
#define AG 8
#define OBSD 256
#define SD 512
#define NACT 32
#define ED 64
#define HYP 256

// ---------------- bf16 helpers / MFMA types ----------------
typedef __attribute__((ext_vector_type(8))) short bf16x8;   // 8 bf16 (4 VGPRs)
typedef __attribute__((ext_vector_type(4))) float f32x4;

__device__ __forceinline__ unsigned short f2bf(float f) {
    unsigned u = __float_as_uint(f);
    u += 0x7fffu + ((u >> 16) & 1u);          // round-to-nearest-even
    return (unsigned short)(u >> 16);
}
__device__ __forceinline__ float bf2f(unsigned short h) {
    return __uint_as_float(((unsigned)h) << 16);
}
#define MFMA16(a,b,c) __builtin_amdgcn_mfma_f32_16x16x32_bf16((a),(b),(c),0,0,0)
#define FRAG(p) (*(const bf16x8*)(p))

// ---------------- ws layout (bytes, all 16B aligned) ----------------
#define WOBS_OFF   0u          // [64][264] bf16
#define WQKV_OFF   33792u      // [192][72] bf16
#define WO_OFF     61440u      // [64][72] bf16
#define WCAT_OFF   70656u      // [640][520] bf16 (Wh1a|Whfa|Wv1|Wb1)
#define WH1B_OFF   736256u     // [512][264] bf16
#define WHFB_OFF   1006592u    // [64][264] bf16
#define ATT_OFF    1040384u    // [16384*8] f32
#define H1A_OFF    1564672u    // [16384][256] bf16
#define HFA_OFF    9953280u    // [16384][256] bf16
#define B1_OFF     18341888u   // [16384][64] bf16
#define VSUM_OFF   20439040u   // [16384] f32
#define WS_NEED    20504576u

// ===========================================================================
// Prep: convert all weight matrices to bf16 with +8-column padded rows.
// ===========================================================================
__global__ __launch_bounds__(256) void k_prep(
    const float* __restrict__ W_obs, const float* __restrict__ Wqkv,
    const float* __restrict__ Wo,
    const float* __restrict__ Wh1a, const float* __restrict__ Whfa,
    const float* __restrict__ Wv1,  const float* __restrict__ Wb1,
    const float* __restrict__ Wh1b, const float* __restrict__ Whfb,
    unsigned char* __restrict__ ws)
{
    unsigned short* wobs = (unsigned short*)(ws + WOBS_OFF);
    unsigned short* wqkv = (unsigned short*)(ws + WQKV_OFF);
    unsigned short* wo   = (unsigned short*)(ws + WO_OFF);
    unsigned short* wcat = (unsigned short*)(ws + WCAT_OFF);
    unsigned short* wh1b = (unsigned short*)(ws + WH1B_OFF);
    unsigned short* whfb = (unsigned short*)(ws + WHFB_OFF);

    const int TOT = 16896 + 13824 + 4608 + 332800 + 135168 + 16896; // 520192
    for (int i = blockIdx.x * 256 + threadIdx.x; i < TOT; i += gridDim.x * 256) {
        int j = i;
        if (j < 16896) {                        // Wobs [64][264], K=256
            int r = j / 264, c = j - r * 264;
            wobs[j] = f2bf(c < 256 ? W_obs[r * 256 + c] : 0.f);
        } else if ((j -= 16896) < 13824) {      // Wqkv [192][72], K=64
            int r = j / 72, c = j - r * 72;
            wqkv[j] = f2bf(c < 64 ? Wqkv[r * 64 + c] : 0.f);
        } else if ((j -= 13824) < 4608) {       // Wo [64][72], K=64
            int r = j / 72, c = j - r * 72;
            wo[j] = f2bf(c < 64 ? Wo[r * 64 + c] : 0.f);
        } else if ((j -= 4608) < 332800) {      // Wcat [640][520], K=512
            int r = j / 520, c = j - r * 520;
            float v = 0.f;
            if (c < 512) {
                if (r < 256)      v = Wh1a[r * 512 + c];
                else if (r < 512) v = Whfa[(r - 256) * 512 + c];
                else if (r < 576) v = Wv1[(r - 512) * 512 + c];
                else              v = Wb1[(r - 576) * 512 + c];
            }
            wcat[j] = f2bf(v);
        } else if ((j -= 332800) < 135168) {    // Wh1b [512][264], K=256
            int r = j / 264, c = j - r * 264;
            wh1b[j] = f2bf(c < 256 ? Wh1b[r * 256 + c] : 0.f);
        } else {                                // Whfb [64][264], K=256
            j -= 135168;
            int r = j / 264, c = j - r * 264;
            whfb[j] = f2bf(c < 256 ? Whfb[r * 256 + c] : 0.f);
        }
    }
}

// ===========================================================================
// K1: encoder + attention -> attended[N, A]. 4 n per block (32 rows), 256 thr.
// Waves: rt=(w&1) row-tile, ch=(w>>1) column-half.
// ===========================================================================
__global__ __launch_bounds__(256, 2) void k_enc(
    const float* __restrict__ agent_qs,
    const float* __restrict__ observations,
    const int*   __restrict__ actions,
    const float* __restrict__ b_obs, const float* __restrict__ W_act,
    const float* __restrict__ b_act, const float* __restrict__ W_q,
    const float* __restrict__ b_q,   const float* __restrict__ bqkv,
    const float* __restrict__ bo,    const float* __restrict__ Wa2q,
    const float* __restrict__ ba2q,
    const unsigned char* __restrict__ ws_w, float* __restrict__ attended)
{
    __shared__ __align__(16) unsigned short s_wA[16896];   // Wobs / Wqkv / Wo
    __shared__ __align__(16) unsigned short s_q[6400];     // obs chunk / qkv / red
    __shared__ __align__(16) unsigned short s_x[2304];     // x / o  [32][72]
    __shared__ __align__(16) float s_p[4][4][8][8];
    __shared__ __align__(16) unsigned short s_wact[2048];  // [64][32] bf16
    __shared__ float s_biasx[64], s_wq[64], s_bo[64], s_wa2q[64], s_bqkv[192];
    __shared__ float s_qs[32];
    __shared__ int   s_acts[32];

    const int t = threadIdx.x;
    const int w = t >> 6, lane = t & 63, m = lane & 15, q = lane >> 4;
    const int rt = w & 1, ch = w >> 1;
    const int R0 = blockIdx.x * 32;            // global (n,a) row base

    const unsigned short* wobs_g = (const unsigned short*)(ws_w + WOBS_OFF);
    const unsigned short* wqkv_g = (const unsigned short*)(ws_w + WQKV_OFF);
    const unsigned short* wo_g   = (const unsigned short*)(ws_w + WO_OFF);

    // ---- stage weights + small tables ----
    for (int i = t; i < 2112; i += 256) ((uint4*)s_wA)[i] = ((const uint4*)wobs_g)[i];
    for (int i = t; i < 2048; i += 256) s_wact[i] = f2bf(W_act[i]);
    if (t < 64) {
        s_biasx[t] = b_obs[t] + b_act[t] + b_q[t];
        s_wq[t] = W_q[t]; s_bo[t] = bo[t]; s_wa2q[t] = Wa2q[t];
    }
    if (t < 192) s_bqkv[t] = bqkv[t];
    if (t < 32) { s_acts[t] = actions[R0 + t]; s_qs[t] = agent_qs[R0 + t]; }
    __syncthreads();

    // ---- Phase B: obs GEMM, K=256 in two 128-chunks ----
    f32x4 acc0[2] = { {0.f,0.f,0.f,0.f}, {0.f,0.f,0.f,0.f} };
    unsigned short* s_obs = s_q;               // [32][136]
    for (int kc = 0; kc < 2; ++kc) {
        #pragma unroll
        for (int c = 0; c < 4; ++c) {
            int u = t + c * 256, row = u >> 5, x = u & 31;
            float4 f = *(const float4*)(observations + (size_t)(R0 + row) * 256 + kc * 128 + x * 4);
            ushort4 h = { f2bf(f.x), f2bf(f.y), f2bf(f.z), f2bf(f.w) };
            *(ushort4*)&s_obs[row * 136 + x * 4] = h;
        }
        __syncthreads();
        #pragma unroll
        for (int ks = 0; ks < 4; ++ks) {
            bf16x8 a = FRAG(&s_obs[(rt * 16 + m) * 136 + ks * 32 + q * 8]);
            #pragma unroll
            for (int tt = 0; tt < 2; ++tt) {
                int ct = ch * 2 + tt;
                bf16x8 b = FRAG(&s_wA[(ct * 16 + m) * 264 + kc * 128 + ks * 32 + q * 8]);
                acc0[tt] = MFMA16(a, b, acc0[tt]);
            }
        }
        __syncthreads();
    }
    // epilogue -> x (bf16, [32][72])
    #pragma unroll
    for (int tt = 0; tt < 2; ++tt) {
        int e = (ch * 2 + tt) * 16 + m;
        #pragma unroll
        for (int r = 0; r < 4; ++r) {
            int row = rt * 16 + q * 4 + r;
            float v = acc0[tt][r] + s_biasx[e] + bf2f(s_wact[e * 32 + s_acts[row]])
                    + s_qs[row] * s_wq[e];
            s_x[row * 72 + e] = f2bf(v);
        }
    }
    __syncthreads();

    // ---- Phase C: qkv GEMM (K=64, 12 col tiles; 6 per wave-half) ----
    for (int i = t; i < 1728; i += 256) ((uint4*)s_wA)[i] = ((const uint4*)wqkv_g)[i];
    __syncthreads();
    f32x4 accq[6];
    #pragma unroll
    for (int tt = 0; tt < 6; ++tt) accq[tt] = (f32x4){0.f,0.f,0.f,0.f};
    #pragma unroll
    for (int ks = 0; ks < 2; ++ks) {
        bf16x8 a = FRAG(&s_x[(rt * 16 + m) * 72 + ks * 32 + q * 8]);
        #pragma unroll
        for (int tt = 0; tt < 6; ++tt) {
            int ct = ch * 6 + tt;
            bf16x8 b = FRAG(&s_wA[(ct * 16 + m) * 72 + ks * 32 + q * 8]);
            accq[tt] = MFMA16(a, b, accq[tt]);
        }
    }
    __syncthreads();   // obs-chunk region now dead; write qkv into s_q [32][200]
    #pragma unroll
    for (int tt = 0; tt < 6; ++tt) {
        int j = (ch * 6 + tt) * 16 + m;
        #pragma unroll
        for (int r = 0; r < 4; ++r) {
            int row = rt * 16 + q * 4 + r;
            s_q[row * 200 + j] = f2bf(accq[tt][r] + s_bqkv[j]);
        }
    }
    __syncthreads();

    // ---- Phase D: attention (VALU). scores+softmax: one (n,h,a) per thread ----
    if (t < 128) {
        int n2 = t >> 5, h = (t >> 3) & 3, a = t & 7;
        int qrow = n2 * 8 + a;
        float qv[16];
        #pragma unroll
        for (int d = 0; d < 16; ++d) qv[d] = bf2f(s_q[qrow * 200 + h * 16 + d]);
        float sc[8], mx = -1e30f;
        #pragma unroll
        for (int b2 = 0; b2 < 8; ++b2) {
            const unsigned short* kr = &s_q[(n2 * 8 + b2) * 200 + 64 + h * 16];
            float s = 0.f;
            #pragma unroll
            for (int d = 0; d < 16; ++d) s += qv[d] * bf2f(kr[d]);
            sc[b2] = s * 0.25f;
            mx = fmaxf(mx, sc[b2]);
        }
        float sum = 0.f;
        #pragma unroll
        for (int b2 = 0; b2 < 8; ++b2) { sc[b2] = __expf(sc[b2] - mx); sum += sc[b2]; }
        float inv = 1.f / sum;
        #pragma unroll
        for (int b2 = 0; b2 < 8; ++b2) s_p[n2][h][a][b2] = sc[b2] * inv;
    }
    __syncthreads();
    #pragma unroll
    for (int g2 = 0; g2 < 8; ++g2) {           // o = p@v -> s_x (reuse as o)
        int idx = t + g2 * 256;
        int row = idx >> 6, e = idx & 63, h = e >> 4, n2 = row >> 3, a = row & 7;
        float ov = 0.f;
        #pragma unroll
        for (int b2 = 0; b2 < 8; ++b2)
            ov += s_p[n2][h][a][b2] * bf2f(s_q[(n2 * 8 + b2) * 200 + 128 + e]);
        s_x[row * 72 + e] = f2bf(ov);
    }
    __syncthreads();

    // ---- Phase E: o-proj (K=64) * Wa2q, reduce -> attended ----
    for (int i = t; i < 576; i += 256) ((uint4*)s_wA)[i] = ((const uint4*)wo_g)[i];
    __syncthreads();
    f32x4 acco[2] = { {0.f,0.f,0.f,0.f}, {0.f,0.f,0.f,0.f} };
    #pragma unroll
    for (int ks = 0; ks < 2; ++ks) {
        bf16x8 a = FRAG(&s_x[(rt * 16 + m) * 72 + ks * 32 + q * 8]);
        #pragma unroll
        for (int tt = 0; tt < 2; ++tt) {
            int ct = ch * 2 + tt;
            bf16x8 b = FRAG(&s_wA[(ct * 16 + m) * 72 + ks * 32 + q * 8]);
            acco[tt] = MFMA16(a, b, acco[tt]);
        }
    }
    float* s_red = (float*)s_q;                // [2][32][16]
    #pragma unroll
    for (int r = 0; r < 4; ++r) {
        float p = 0.f;
        #pragma unroll
        for (int tt = 0; tt < 2; ++tt) {
            int e = (ch * 2 + tt) * 16 + m;
            p += (acco[tt][r] + s_bo[e]) * s_wa2q[e];
        }
        s_red[(ch * 32 + rt * 16 + q * 4 + r) * 16 + m] = p;
    }
    __syncthreads();
    if (t < 32) {
        float s = ba2q[0];
        #pragma unroll
        for (int mm = 0; mm < 16; ++mm) s += s_red[t * 16 + mm] + s_red[512 + t * 16 + mm];
        attended[R0 + t] = s;
    }
}

// ===========================================================================
// K2a: hypernet layer-1: st -> h1a, hfa (relu, bf16), b1 (bf16), vsum (f32).
// 64 n per block, grid 256 (1/CU). Wave = row-tile; all 40 col-tiles per wave.
// ===========================================================================
__global__ __launch_bounds__(256, 1) void k_hyp1(
    const float* __restrict__ states,
    const float* __restrict__ bh1a, const float* __restrict__ bhfa,
    const float* __restrict__ bv1,  const float* __restrict__ bb1,
    const float* __restrict__ Wv2,
    const unsigned char* __restrict__ ws_w, unsigned char* __restrict__ ws_o)
{
    __shared__ __align__(16) unsigned short s_st[64 * 136];
    __shared__ __align__(16) unsigned short s_w[64 * 136];
    __shared__ float s_biasc[640], s_wv2[64];
    __shared__ float s_red[64 * 16];

    const int t = threadIdx.x;
    const int w = t >> 6, lane = t & 63, m = lane & 15, q = lane >> 4;
    const int n0 = blockIdx.x * 64;
    const unsigned short* wcat = (const unsigned short*)(ws_w + WCAT_OFF);
    unsigned short* h1a_ws = (unsigned short*)(ws_o + H1A_OFF);
    unsigned short* hfa_ws = (unsigned short*)(ws_o + HFA_OFF);
    unsigned short* b1_ws  = (unsigned short*)(ws_o + B1_OFF);
    float* vsum_ws = (float*)(ws_o + VSUM_OFF);

    for (int i = t; i < 640; i += 256)
        s_biasc[i] = (i < 256) ? bh1a[i] : (i < 512) ? bhfa[i - 256]
                   : (i < 576) ? bv1[i - 512] : bb1[i - 576];
    if (t < 64) s_wv2[t] = Wv2[t];

    f32x4 acc[40];
    #pragma unroll
    for (int i = 0; i < 40; ++i) acc[i] = (f32x4){0.f,0.f,0.f,0.f};

    for (int kc = 0; kc < 4; ++kc) {
        #pragma unroll
        for (int c = 0; c < 8; ++c) {          // stage st chunk [64][128]
            int u = t + c * 256, row = u >> 5, x = u & 31;
            float4 f = *(const float4*)(states + (size_t)(n0 + row) * 512 + kc * 128 + x * 4);
            ushort4 h = { f2bf(f.x), f2bf(f.y), f2bf(f.z), f2bf(f.w) };
            *(ushort4*)&s_st[row * 136 + x * 4] = h;
        }
        __syncthreads();
        #pragma unroll
        for (int cg = 0; cg < 10; ++cg) {
            #pragma unroll
            for (int c = 0; c < 4; ++c) {      // stage Wcat chunk [64 cols][128]
                int u = t + c * 256, jl = u >> 4, x16 = u & 15;
                *(uint4*)&s_w[jl * 136 + x16 * 8] =
                    *(const uint4*)&wcat[(size_t)(cg * 64 + jl) * 520 + kc * 128 + x16 * 8];
            }
            __syncthreads();
            #pragma unroll
            for (int ks = 0; ks < 4; ++ks) {
                bf16x8 a = FRAG(&s_st[(w * 16 + m) * 136 + ks * 32 + q * 8]);
                #pragma unroll
                for (int tt = 0; tt < 4; ++tt) {
                    bf16x8 b = FRAG(&s_w[(tt * 16 + m) * 136 + ks * 32 + q * 8]);
                    acc[cg * 4 + tt] = MFMA16(a, b, acc[cg * 4 + tt]);
                }
            }
            __syncthreads();
        }
    }
    // epilogue
    float vps[4] = {0.f, 0.f, 0.f, 0.f};
    #pragma unroll
    for (int cgtt = 0; cgtt < 40; ++cgtt) {
        int jj = cgtt * 16 + m;
        #pragma unroll
        for (int r = 0; r < 4; ++r) {
            int row = w * 16 + q * 4 + r;
            float D = acc[cgtt][r] + s_biasc[jj];
            if (cgtt < 16)      h1a_ws[(size_t)(n0 + row) * 256 + jj] = f2bf(fmaxf(D, 0.f));
            else if (cgtt < 32) hfa_ws[(size_t)(n0 + row) * 256 + (jj - 256)] = f2bf(fmaxf(D, 0.f));
            else if (cgtt < 36) vps[r] += fmaxf(D, 0.f) * s_wv2[jj - 512];
            else                b1_ws[(size_t)(n0 + row) * 64 + (jj - 576)] = f2bf(D);
        }
    }
    #pragma unroll
    for (int r = 0; r < 4; ++r) s_red[(w * 16 + q * 4 + r) * 16 + m] = vps[r];
    __syncthreads();
    if (t < 64) {
        float s = 0.f;
        #pragma unroll
        for (int mm = 0; mm < 16; ++mm) s += s_red[t * 16 + mm];
        vsum_ws[n0 + t] = s;
    }
}

// ===========================================================================
// K2b: hypernet layer-2 + mix -> out[N]. 64 n per block, grid 256.
// ===========================================================================
__global__ __launch_bounds__(256, 1) void k_mix(
    const float* __restrict__ bh1b, const float* __restrict__ bhfb,
    const float* __restrict__ bv2,
    const unsigned char* __restrict__ ws, float* __restrict__ out)
{
    __shared__ __align__(16) unsigned short s_A[64 * 264];   // h1a then hfa
    __shared__ __align__(16) unsigned short s_w[64 * 72];
    __shared__ __align__(16) unsigned short s_b1[64 * 64];
    __shared__ float s_aq[512], s_bh1b[512], s_bhfb[64], s_red[64 * 16];

    const int t = threadIdx.x;
    const int w = t >> 6, lane = t & 63, m = lane & 15, q = lane >> 4;
    const int n0 = blockIdx.x * 64;

    const unsigned short* wh1b = (const unsigned short*)(ws + WH1B_OFF);
    const unsigned short* whfb = (const unsigned short*)(ws + WHFB_OFF);
    const float* attended = (const float*)(ws + ATT_OFF);
    const unsigned short* h1a_ws = (const unsigned short*)(ws + H1A_OFF);
    const unsigned short* hfa_ws = (const unsigned short*)(ws + HFA_OFF);
    const unsigned short* b1_ws  = (const unsigned short*)(ws + B1_OFF);
    const float* vsum_ws = (const float*)(ws + VSUM_OFF);

    s_aq[t] = attended[(size_t)n0 * 8 + t];
    s_aq[t + 256] = attended[(size_t)n0 * 8 + 256 + t];
    s_bh1b[t] = bh1b[t]; s_bh1b[t + 256] = bh1b[t + 256];
    if (t < 64) s_bhfb[t] = bhfb[t];
    #pragma unroll
    for (int c = 0; c < 2; ++c)
        ((uint4*)s_b1)[t + c * 256] = ((const uint4*)(b1_ws + (size_t)n0 * 64))[t + c * 256];
    #pragma unroll
    for (int c = 0; c < 8; ++c) {              // stage h1a [64][256] -> [64][264]
        int u = t + c * 256, row = u >> 5, x = u & 31;
        *(uint4*)&s_A[row * 264 + x * 8] = *(const uint4*)&h1a_ws[(size_t)(n0 + row) * 256 + x * 8];
    }
    __syncthreads();

    f32x4 hid[4];
    #pragma unroll
    for (int i = 0; i < 4; ++i) hid[i] = (f32x4){0.f,0.f,0.f,0.f};

    for (int cg = 0; cg < 8; ++cg) {           // w1 cols, a = cg
        f32x4 acc[4];
        #pragma unroll
        for (int i = 0; i < 4; ++i) acc[i] = (f32x4){0.f,0.f,0.f,0.f};
        for (int kc = 0; kc < 4; ++kc) {
            #pragma unroll
            for (int c = 0; c < 2; ++c) {      // stage Wh1b chunk [64 cols][64 k]
                int u = t + c * 256, jl = u >> 3, x8 = u & 7;
                *(uint4*)&s_w[jl * 72 + x8 * 8] =
                    *(const uint4*)&wh1b[(size_t)(cg * 64 + jl) * 264 + kc * 64 + x8 * 8];
            }
            __syncthreads();
            #pragma unroll
            for (int ks = 0; ks < 2; ++ks) {
                bf16x8 a = FRAG(&s_A[(w * 16 + m) * 264 + kc * 64 + ks * 32 + q * 8]);
                #pragma unroll
                for (int tt = 0; tt < 4; ++tt) {
                    bf16x8 b = FRAG(&s_w[(tt * 16 + m) * 72 + ks * 32 + q * 8]);
                    acc[tt] = MFMA16(a, b, acc[tt]);
                }
            }
            __syncthreads();
        }
        #pragma unroll
        for (int tt = 0; tt < 4; ++tt) {
            int jj = (cg * 4 + tt) * 16 + m;
            #pragma unroll
            for (int r = 0; r < 4; ++r) {
                int row = w * 16 + q * 4 + r;
                hid[tt][r] += s_aq[row * 8 + cg] * fabsf(acc[tt][r] + s_bh1b[jj]);
            }
        }
    }

    __syncthreads();
    #pragma unroll
    for (int c = 0; c < 8; ++c) {              // restage A <- hfa
        int u = t + c * 256, row = u >> 5, x = u & 31;
        *(uint4*)&s_A[row * 264 + x * 8] = *(const uint4*)&hfa_ws[(size_t)(n0 + row) * 256 + x * 8];
    }
    __syncthreads();

    f32x4 wfa[4];
    #pragma unroll
    for (int i = 0; i < 4; ++i) wfa[i] = (f32x4){0.f,0.f,0.f,0.f};
    for (int kc = 0; kc < 4; ++kc) {
        #pragma unroll
        for (int c = 0; c < 2; ++c) {
            int u = t + c * 256, jl = u >> 3, x8 = u & 7;
            *(uint4*)&s_w[jl * 72 + x8 * 8] =
                *(const uint4*)&whfb[(size_t)jl * 264 + kc * 64 + x8 * 8];
        }
        __syncthreads();
        #pragma unroll
        for (int ks = 0; ks < 2; ++ks) {
            bf16x8 a = FRAG(&s_A[(w * 16 + m) * 264 + kc * 64 + ks * 32 + q * 8]);
            #pragma unroll
            for (int tt = 0; tt < 4; ++tt) {
                bf16x8 b = FRAG(&s_w[(tt * 16 + m) * 72 + ks * 32 + q * 8]);
                wfa[tt] = MFMA16(a, b, wfa[tt]);
            }
        }
        __syncthreads();
    }
    #pragma unroll
    for (int r = 0; r < 4; ++r) {
        int row = w * 16 + q * 4 + r;
        float part = 0.f;
        #pragma unroll
        for (int tt = 0; tt < 4; ++tt) {
            int e = tt * 16 + m;
            float wf = fabsf(wfa[tt][r] + s_bhfb[e]);
            float hv = hid[tt][r] + bf2f(s_b1[row * 64 + e]);
            hv = (hv > 0.f) ? hv : expm1f(hv);
            part += wf * hv;
        }
        s_red[row * 16 + m] = part;
    }
    __syncthreads();
    if (t < 64) {
        float y = bv2[0] + vsum_ws[n0 + t];
        #pragma unroll
        for (int mm = 0; mm < 16; ++mm) y += s_red[t * 16 + mm];
        out[n0 + t] = y;
    }
}

// ===========================================================================
// Fallback (round-1, validated) kernels — used if ws_size is too small.
// ===========================================================================
#define NBF 16
__global__ __launch_bounds__(256) void k_enc_attn_fb(
    const float* __restrict__ agent_qs, const float* __restrict__ observations,
    const int* __restrict__ actions,
    const float* __restrict__ W_obs, const float* __restrict__ b_obs,
    const float* __restrict__ W_act, const float* __restrict__ b_act,
    const float* __restrict__ W_q,   const float* __restrict__ b_q,
    const float* __restrict__ Wqkv,  const float* __restrict__ bqkv,
    const float* __restrict__ Wo,    const float* __restrict__ bo,
    const float* __restrict__ Wa2q,  const float* __restrict__ ba2q,
    float* __restrict__ attended)
{
    __shared__ __align__(16) float s_obs[AG][OBSD];
    __shared__ __align__(16) float s_x[AG][ED];
    __shared__ __align__(16) float s_qkv[AG][3*ED];
    __shared__ float s_p[4][AG][AG];
    __shared__ __align__(16) float s_o[AG][ED];
    const int n = blockIdx.x, t = threadIdx.x;
    { const float4* g = (const float4*)(observations + (size_t)n*(AG*OBSD));
      float4* s4 = (float4*)&s_obs[0][0];
      for (int i = 0; i < 2; ++i) s4[t + i*256] = g[t + i*256]; }
    __syncthreads();
    { const int e = t & 63, a0 = t >> 6;
      const float wq = W_q[e]; const float bias0 = b_obs[e]+b_act[e]+b_q[e];
      const float* wrow = W_obs + e*OBSD;
      for (int g = 0; g < 2; ++g) { const int a = a0 + g*4; float acc = 0.f;
        for (int k = 0; k < OBSD; k += 4) { const float4 wv = *(const float4*)(wrow+k);
          acc += wv.x*s_obs[a][k]+wv.y*s_obs[a][k+1]+wv.z*s_obs[a][k+2]+wv.w*s_obs[a][k+3]; }
        s_x[a][e] = acc + bias0 + W_act[e*NACT + actions[n*AG+a]] + agent_qs[n*AG+a]*wq; } }
    __syncthreads();
    for (int g = 0; g < 6; ++g) { const int i = t + g*256, a = i/192, j = i - a*192;
      const float* wrow = Wqkv + j*ED; float acc = bqkv[j];
      for (int k = 0; k < ED; k += 4) { const float4 wv = *(const float4*)(wrow+k);
        acc += wv.x*s_x[a][k]+wv.y*s_x[a][k+1]+wv.z*s_x[a][k+2]+wv.w*s_x[a][k+3]; }
      s_qkv[a][j] = acc; }
    __syncthreads();
    { const int h = t>>6, a = (t>>3)&7, b = t&7; float acc = 0.f;
      for (int d = 0; d < 16; ++d) acc += s_qkv[a][h*16+d]*s_qkv[b][64+h*16+d];
      s_p[h][a][b] = acc*0.25f; }
    __syncthreads();
    if (t < 32) { const int h = t>>3, a = t&7; float mm = -1e30f;
      for (int b = 0; b < 8; ++b) mm = fmaxf(mm, s_p[h][a][b]);
      float ex[8], sum = 0.f;
      for (int b = 0; b < 8; ++b) { ex[b] = __expf(s_p[h][a][b]-mm); sum += ex[b]; }
      for (int b = 0; b < 8; ++b) s_p[h][a][b] = ex[b]/sum; }
    __syncthreads();
    for (int g = 0; g < 2; ++g) { const int i = t+g*256, a = i>>6, c = i&63, h = c>>4;
      float acc = 0.f;
      for (int b = 0; b < 8; ++b) acc += s_p[h][a][b]*s_qkv[b][128+c];
      s_o[a][c] = acc; }
    __syncthreads();
    for (int g = 0; g < 2; ++g) { const int i = t+g*256, a = i>>6, e2 = i&63;
      const float* wrow = Wo + e2*ED; float acc = bo[e2];
      for (int k = 0; k < ED; k += 4) { const float4 wv = *(const float4*)(wrow+k);
        acc += wv.x*s_o[a][k]+wv.y*s_o[a][k+1]+wv.z*s_o[a][k+2]+wv.w*s_o[a][k+3]; }
      s_x[a][e2] = acc * Wa2q[e2]; }
    __syncthreads();
    if (t < 8) { float s = ba2q[0];
      for (int e2 = 0; e2 < 64; ++e2) s += s_x[t][e2];
      attended[n*AG+t] = s; }
}

__global__ __launch_bounds__(256) void k_mixer_fb(
    const float* __restrict__ states, const float* __restrict__ attended,
    const float* __restrict__ Wh1a, const float* __restrict__ bh1a,
    const float* __restrict__ Wh1b, const float* __restrict__ bh1b,
    const float* __restrict__ Whfa, const float* __restrict__ bhfa,
    const float* __restrict__ Whfb, const float* __restrict__ bhfb,
    const float* __restrict__ Wb1,  const float* __restrict__ bb1,
    const float* __restrict__ Wv1,  const float* __restrict__ bv1,
    const float* __restrict__ Wv2,  const float* __restrict__ bv2,
    float* __restrict__ out)
{
    __shared__ __align__(16) float s_st[NBF][SD];
    __shared__ __align__(16) float s_h[NBF][HYP];
    __shared__ __align__(16) float s_hid[NBF][ED];
    __shared__ __align__(16) float s_prod[NBF][ED];
    __shared__ __align__(16) float s_v[NBF][ED];
    __shared__ float s_aq[NBF][AG];
    const int n0 = blockIdx.x * NBF, t = threadIdx.x;
    { const float4* g = (const float4*)(states + (size_t)n0*SD);
      float4* s4 = (float4*)&s_st[0][0];
      for (int i = 0; i < 8; ++i) s4[t + i*256] = g[t + i*256];
      if (t < NBF*AG) ((float*)s_aq)[t] = attended[n0*AG + t]; }
    __syncthreads();
    { const float* wrow = Wh1a + t*SD; float acc[NBF];
      for (int n = 0; n < NBF; ++n) acc[n] = 0.f;
      for (int k = 0; k < SD; k += 4) { const float4 wv = *(const float4*)(wrow+k);
        for (int n = 0; n < NBF; ++n) { const float4 x = *(const float4*)(&s_st[n][k]);
          acc[n] += wv.x*x.x+wv.y*x.y+wv.z*x.z+wv.w*x.w; } }
      const float bb = bh1a[t];
      for (int n = 0; n < NBF; ++n) s_h[n][t] = fmaxf(acc[n]+bb, 0.f); }
    for (int g = 0; g < 4; ++g) { const int i = t+g*256, n = i>>6, e = i&63;
      const float* wrow = Wb1 + e*SD; float acc = bb1[e];
      for (int k = 0; k < SD; k += 4) { const float4 wv = *(const float4*)(wrow+k);
        const float4 x = *(const float4*)(&s_st[n][k]);
        acc += wv.x*x.x+wv.y*x.y+wv.z*x.z+wv.w*x.w; }
      s_hid[n][e] = acc; }
    __syncthreads();
    for (int g = 0; g < 2; ++g) { const int j = t+g*256;
      const float* wrow = Wh1b + j*HYP; float acc[NBF];
      for (int n = 0; n < NBF; ++n) acc[n] = 0.f;
      for (int k = 0; k < HYP; k += 4) { const float4 wv = *(const float4*)(wrow+k);
        for (int n = 0; n < NBF; ++n) { const float4 x = *(const float4*)(&s_h[n][k]);
          acc[n] += wv.x*x.x+wv.y*x.y+wv.z*x.z+wv.w*x.w; } }
      const float bb = bh1b[j]; const int a = j>>6, e = j&63;
      for (int n = 0; n < NBF; ++n)
        atomicAdd(&s_hid[n][e], s_aq[n][a]*fabsf(acc[n]+bb)); }
    __syncthreads();
    { const float* wrow = Whfa + t*SD; float acc[NBF];
      for (int n = 0; n < NBF; ++n) acc[n] = 0.f;
      for (int k = 0; k < SD; k += 4) { const float4 wv = *(const float4*)(wrow+k);
        for (int n = 0; n < NBF; ++n) { const float4 x = *(const float4*)(&s_st[n][k]);
          acc[n] += wv.x*x.x+wv.y*x.y+wv.z*x.z+wv.w*x.w; } }
      const float bb = bhfa[t];
      for (int n = 0; n < NBF; ++n) s_h[n][t] = fmaxf(acc[n]+bb, 0.f); }
    __syncthreads();
    for (int g = 0; g < 4; ++g) { const int i = t+g*256, n = i>>6, e = i&63;
      { const float* wrow = Whfb + e*HYP; float acc = bhfb[e];
        for (int k = 0; k < HYP; k += 4) { const float4 wv = *(const float4*)(wrow+k);
          const float4 x = *(const float4*)(&s_h[n][k]);
          acc += wv.x*x.x+wv.y*x.y+wv.z*x.z+wv.w*x.w; }
        float h = s_hid[n][e]; h = (h > 0.f) ? h : expm1f(h);
        s_prod[n][e] = fabsf(acc)*h; }
      { const float* wrow = Wv1 + e*SD; float acc = bv1[e];
        for (int k = 0; k < SD; k += 4) { const float4 wv = *(const float4*)(wrow+k);
          const float4 x = *(const float4*)(&s_st[n][k]);
          acc += wv.x*x.x+wv.y*x.y+wv.z*x.z+wv.w*x.w; }
        s_v[n][e] = fmaxf(acc, 0.f)*Wv2[e]; } }
    __syncthreads();
    if (t < NBF) { float y = bv2[0];
      for (int e = 0; e < ED; ++e) y += s_prod[t][e] + s_v[t][e];
      out[n0+t] = y; }
}

// ===========================================================================
extern "C" void kernel_launch(void* const* d_in, const int* in_sizes, int n_in,
                              void* d_out, int out_size, void* d_ws, size_t ws_size,
                              hipStream_t stream) {
    const float* agent_qs     = (const float*)d_in[0];
    const float* states       = (const float*)d_in[1];
    const float* observations = (const float*)d_in[2];
    const int*   actions      = (const int*)  d_in[3];
    const float* W_obs = (const float*)d_in[4];  const float* b_obs = (const float*)d_in[5];
    const float* W_act = (const float*)d_in[6];  const float* b_act = (const float*)d_in[7];
    const float* W_q   = (const float*)d_in[8];  const float* b_q   = (const float*)d_in[9];
    const float* Wqkv  = (const float*)d_in[10]; const float* bqkv  = (const float*)d_in[11];
    const float* Wo    = (const float*)d_in[12]; const float* bo    = (const float*)d_in[13];
    const float* Wa2q  = (const float*)d_in[14]; const float* ba2q  = (const float*)d_in[15];
    const float* Wh1a  = (const float*)d_in[16]; const float* bh1a  = (const float*)d_in[17];
    const float* Wh1b  = (const float*)d_in[18]; const float* bh1b  = (const float*)d_in[19];
    const float* Whfa  = (const float*)d_in[20]; const float* bhfa  = (const float*)d_in[21];
    const float* Whfb  = (const float*)d_in[22]; const float* bhfb  = (const float*)d_in[23];
    const float* Wb1   = (const float*)d_in[24]; const float* bb1   = (const float*)d_in[25];
    const float* Wv1   = (const float*)d_in[26]; const float* bv1   = (const float*)d_in[27];
    const float* Wv2   = (const float*)d_in[28]; const float* bv2   = (const float*)d_in[29];
    float* out = (float*)d_out;

    if (ws_size >= WS_NEED) {
        unsigned char* ws = (unsigned char*)d_ws;
        float* attended = (float*)(ws + ATT_OFF);
        k_prep<<<512, 256, 0, stream>>>(W_obs, Wqkv, Wo, Wh1a, Whfa, Wv1, Wb1,
                                        Wh1b, Whfb, ws);
        k_enc<<<N_TOT / 4, 256, 0, stream>>>(agent_qs, observations, actions,
                                             b_obs, W_act, b_act, W_q, b_q,
                                             bqkv, bo, Wa2q, ba2q, ws, attended);
        k_hyp1<<<N_TOT / 64, 256, 0, stream>>>(states, bh1a, bhfa, bv1, bb1, Wv2,
                                               ws, ws);
        k_mix<<<N_TOT / 64, 256, 0, stream>>>(bh1b, bhfb, bv2, ws, out);
    } else {
        float* attended = (float*)d_ws;
        k_enc_attn_fb<<<N_TOT, 256, 0, stream>>>(agent_qs, observations, actions,
            W_obs, b_obs, W_act, b_act, W_q, b_q, Wqkv, bqkv, Wo, bo, Wa2q, ba2q, attended);
        k_mixer_fb<<<N_TOT / NBF, 256, 0, stream>>>(states, attended,
            Wh1a, bh1a, Wh1b, bh1b, Whfa, bhfa, Whfb, bhfb,
            Wb1, bb1, Wv1, bv1, Wv2, bv2, out);
    }
}

// Round 3
// 348.882 us; speedup vs baseline: 9.1630x; 1.2683x over previous
//
#include <hip/hip_runtime.h>
#include <hip/hip_bf16.h>
#include <math.h>

// Shapes (compile-time)
#define N_TOT 16384   // B*T
#define AG 8
#define OBSD 256
#define SD 512
#define NACT 32
#define ED 64
#define HYP 256

// ---------------- bf16 helpers / MFMA types ----------------
typedef __attribute__((ext_vector_type(8))) short bf16x8;   // 8 bf16 (4 VGPRs)
typedef __attribute__((ext_vector_type(4))) float f32x4;

__device__ __forceinline__ unsigned short f2bf(float f) {
    unsigned u = __float_as_uint(f);
    u += 0x7fffu + ((u >> 16) & 1u);          // round-to-nearest-even
    return (unsigned short)(u >> 16);
}
__device__ __forceinline__ float bf2f(unsigned short h) {
    return __uint_as_float(((unsigned)h) << 16);
}
#define MFMA16(a,b,c) __builtin_amdgcn_mfma_f32_16x16x32_bf16((a),(b),(c),0,0,0)
#define FRAG(p) (*(const bf16x8*)(p))

// ---------------- ws layout (bytes, 16B aligned) ----------------
#define WC_OFF     0u            // [192][264] bf16  (Wqkv @ Wobs folded)
#define WCAT_OFF   101376u       // [640][520] bf16 (Wh1a|Whfa|Wv1|Wb1)
#define WH1B_OFF   766976u       // [512][264] bf16
#define WHFB_OFF   1037312u      // [64][264] bf16
#define ACTTAB_OFF 1071104u      // [32][192] f32
#define WQEFF_OFF  1095680u      // [192] f32
#define BIASQ_OFF  1096448u      // [192] f32
#define WEFF_OFF   1097216u      // [64] f32
#define CATT_OFF   1097472u      // [1] f32 (+pad)
#define ATT_OFF    1097536u      // [16384*8] f32
#define H1A_OFF    1621824u      // [16384][256] bf16
#define HFA_OFF    10010432u     // [16384][256] bf16
#define B1_OFF     18399040u     // [16384][64] bf16
#define VSUM_OFF   20496192u     // [16384] f32
#define WS_NEED    20561728u

// ===========================================================================
// Prep: weight conversion + algebraic folding (fp32 dots, then bf16 cast).
// ===========================================================================
__global__ __launch_bounds__(256) void k_prep(
    const float* __restrict__ W_obs, const float* __restrict__ W_act,
    const float* __restrict__ W_q,   const float* __restrict__ b_obs,
    const float* __restrict__ b_act, const float* __restrict__ b_q,
    const float* __restrict__ Wqkv,  const float* __restrict__ bqkv,
    const float* __restrict__ Wo,    const float* __restrict__ bo,
    const float* __restrict__ Wa2q,  const float* __restrict__ ba2q,
    const float* __restrict__ Wh1a, const float* __restrict__ Whfa,
    const float* __restrict__ Wv1,  const float* __restrict__ Wb1,
    const float* __restrict__ Wh1b, const float* __restrict__ Whfb,
    unsigned char* __restrict__ ws)
{
    unsigned short* wcat = (unsigned short*)(ws + WCAT_OFF);
    unsigned short* wh1b = (unsigned short*)(ws + WH1B_OFF);
    unsigned short* whfb = (unsigned short*)(ws + WHFB_OFF);
    unsigned short* wc   = (unsigned short*)(ws + WC_OFF);
    float* acttab = (float*)(ws + ACTTAB_OFF);
    float* wqeff  = (float*)(ws + WQEFF_OFF);
    float* biasq  = (float*)(ws + BIASQ_OFF);
    float* weff   = (float*)(ws + WEFF_OFF);
    float* catt   = (float*)(ws + CATT_OFF);

    const int TOT = 332800 + 135168 + 16896 + 49152 + 6144 + 192 + 192 + 64 + 1;
    for (int i = blockIdx.x * 256 + threadIdx.x; i < TOT; i += gridDim.x * 256) {
        int j = i;
        if (j < 332800) {                       // Wcat [640][520], K=512
            int r = j / 520, c = j - r * 520;
            float v = 0.f;
            if (c < 512) {
                if (r < 256)      v = Wh1a[r * 512 + c];
                else if (r < 512) v = Whfa[(r - 256) * 512 + c];
                else if (r < 576) v = Wv1[(r - 512) * 512 + c];
                else              v = Wb1[(r - 576) * 512 + c];
            }
            wcat[j] = f2bf(v);
        } else if ((j -= 332800) < 135168) {    // Wh1b [512][264], K=256
            int r = j / 264, c = j - r * 264;
            wh1b[j] = f2bf(c < 256 ? Wh1b[r * 256 + c] : 0.f);
        } else if ((j -= 135168) < 16896) {     // Whfb [64][264], K=256
            int r = j / 264, c = j - r * 264;
            whfb[j] = f2bf(c < 256 ? Whfb[r * 256 + c] : 0.f);
        } else if ((j -= 16896) < 49152) {      // Wc = Wqkv @ Wobs : [192][256]
            int r = j >> 8, c = j & 255;
            float s = 0.f;
            #pragma unroll 8
            for (int e = 0; e < 64; ++e) s += Wqkv[r * 64 + e] * W_obs[e * 256 + c];
            wc[r * 264 + c] = f2bf(s);
        } else if ((j -= 49152) < 6144) {       // acttab[act][r] = Wqkv @ W_act[:,act]
            int r = j >> 5, act = j & 31;
            float s = 0.f;
            #pragma unroll 8
            for (int e = 0; e < 64; ++e) s += Wqkv[r * 64 + e] * W_act[e * 32 + act];
            acttab[act * 192 + r] = s;
        } else if ((j -= 6144) < 192) {         // wqeff = Wqkv @ W_q[:,0]
            float s = 0.f;
            #pragma unroll 8
            for (int e = 0; e < 64; ++e) s += Wqkv[j * 64 + e] * W_q[e];
            wqeff[j] = s;
        } else if ((j -= 192) < 192) {          // biasq = Wqkv@(b_obs+b_act+b_q)+bqkv
            float s = bqkv[j];
            #pragma unroll 8
            for (int e = 0; e < 64; ++e)
                s += Wqkv[j * 64 + e] * (b_obs[e] + b_act[e] + b_q[e]);
            biasq[j] = s;
        } else if ((j -= 192) < 64) {           // weff[e] = sum_e' Wa2q[e']*Wo[e'][e]
            float s = 0.f;
            #pragma unroll 8
            for (int e2 = 0; e2 < 64; ++e2) s += Wa2q[e2] * Wo[e2 * 64 + j];
            weff[j] = s;
        } else {                                // catt = dot(bo,Wa2q)+ba2q
            float s = ba2q[0];
            #pragma unroll 8
            for (int e2 = 0; e2 < 64; ++e2) s += bo[e2] * Wa2q[e2];
            catt[0] = s;
        }
    }
}

// ===========================================================================
// K1 v2: encoder+attention via folded Wc. 512 blocks x 8 tiles of 32 rows.
// Wc fragments in registers; register prefetch of next obs tile.
// ===========================================================================
#define TPB_TILES 8
__global__ __launch_bounds__(256, 2) void k_enc(
    const float* __restrict__ agent_qs,
    const float* __restrict__ observations,
    const int*   __restrict__ actions,
    const unsigned char* __restrict__ ws_w, float* __restrict__ attended)
{
    __shared__ __align__(16) unsigned short s_obs[32 * 264];
    __shared__ __align__(16) unsigned short s_qkv[32 * 200];
    __shared__ __align__(16) float s_att_tab[32 * 192];
    __shared__ __align__(16) float s_p[4][4][8][8];
    __shared__ float s_vw[4][8][4];
    __shared__ float s_weff[64], s_biasq[192], s_wqeff[192];
    __shared__ float s_qs[32], s_catt;
    __shared__ int   s_acts[32];

    const int t = threadIdx.x;
    const int w = t >> 6, lane = t & 63, m = lane & 15, q = lane >> 4;

    const unsigned short* wc = (const unsigned short*)(ws_w + WC_OFF);
    const float* acttab_g = (const float*)(ws_w + ACTTAB_OFF);
    const float* wqeff_g  = (const float*)(ws_w + WQEFF_OFF);
    const float* biasq_g  = (const float*)(ws_w + BIASQ_OFF);
    const float* weff_g   = (const float*)(ws_w + WEFF_OFF);
    const float* catt_g   = (const float*)(ws_w + CATT_OFF);

    // block-start staging of small tables
    for (int i = t; i < 1536; i += 256)
        ((float4*)s_att_tab)[i] = ((const float4*)acttab_g)[i];
    if (t < 192) { s_biasq[t] = biasq_g[t]; s_wqeff[t] = wqeff_g[t]; }
    if (t < 64)  s_weff[t] = weff_g[t];
    if (t == 0)  s_catt = catt_g[0];

    // Wc fragments in registers: wave w owns col-tiles w*3..w*3+2
    bf16x8 wf[3][8];
    #pragma unroll
    for (int ctl = 0; ctl < 3; ++ctl)
        #pragma unroll
        for (int kc = 0; kc < 8; ++kc)
            wf[ctl][kc] = FRAG(&wc[((w * 3 + ctl) * 16 + m) * 264 + kc * 32 + q * 8]);

    const int tb = blockIdx.x * TPB_TILES;
    const float4* obs4 = (const float4*)observations;

    // prefetch tile 0
    float4 pf[8];
    {
        const int R0 = tb * 32;
        #pragma unroll
        for (int c = 0; c < 8; ++c) {
            int u = t + c * 256, row = u >> 6, x4 = u & 63;
            pf[c] = obs4[(size_t)(R0 + row) * 64 + x4];
        }
    }

    for (int it = 0; it < TPB_TILES; ++it) {
        const int R0 = (tb + it) * 32;
        // stage: cvt prefetched obs -> LDS bf16 [32][264]
        #pragma unroll
        for (int c = 0; c < 8; ++c) {
            int u = t + c * 256, row = u >> 6, x4 = u & 63;
            float4 f = pf[c];
            ushort4 h = { f2bf(f.x), f2bf(f.y), f2bf(f.z), f2bf(f.w) };
            *(ushort4*)&s_obs[row * 264 + x4 * 4] = h;
        }
        if (t < 32) { s_acts[t] = actions[R0 + t]; s_qs[t] = agent_qs[R0 + t]; }
        __syncthreads();                       // B_a
        // prefetch next tile (overlaps with compute below)
        if (it + 1 < TPB_TILES) {
            const int R1 = (tb + it + 1) * 32;
            #pragma unroll
            for (int c = 0; c < 8; ++c) {
                int u = t + c * 256, row = u >> 6, x4 = u & 63;
                pf[c] = obs4[(size_t)(R1 + row) * 64 + x4];
            }
        }
        // qkv GEMM: K=256, 12 col-tiles (3/wave), 2 row-tiles
        f32x4 acc[2][3];
        #pragma unroll
        for (int r2 = 0; r2 < 2; ++r2)
            #pragma unroll
            for (int c2 = 0; c2 < 3; ++c2) acc[r2][c2] = (f32x4){0.f,0.f,0.f,0.f};
        #pragma unroll
        for (int kc = 0; kc < 8; ++kc) {
            bf16x8 a0 = FRAG(&s_obs[(m)      * 264 + kc * 32 + q * 8]);
            bf16x8 a1 = FRAG(&s_obs[(16 + m) * 264 + kc * 32 + q * 8]);
            #pragma unroll
            for (int ctl = 0; ctl < 3; ++ctl) {
                acc[0][ctl] = MFMA16(a0, wf[ctl][kc], acc[0][ctl]);
                acc[1][ctl] = MFMA16(a1, wf[ctl][kc], acc[1][ctl]);
            }
        }
        // epilogue -> s_qkv [32][200] bf16
        #pragma unroll
        for (int rtl = 0; rtl < 2; ++rtl)
            #pragma unroll
            for (int ctl = 0; ctl < 3; ++ctl) {
                int j = (w * 3 + ctl) * 16 + m;
                #pragma unroll
                for (int r = 0; r < 4; ++r) {
                    int row = rtl * 16 + q * 4 + r;
                    float v = acc[rtl][ctl][r] + s_biasq[j]
                            + s_att_tab[s_acts[row] * 192 + j]
                            + s_qs[row] * s_wqeff[j];
                    s_qkv[row * 200 + j] = f2bf(v);
                }
            }
        __syncthreads();                       // B_b
        // attention: softmax (t<128) || vw (t>=128)
        if (t < 128) {
            int n2 = t >> 5, h = (t >> 3) & 3, a = t & 7;
            int qrow = n2 * 8 + a;
            float qv[16];
            {
                bf16x8 qa = FRAG(&s_qkv[qrow * 200 + h * 16]);
                bf16x8 qb = FRAG(&s_qkv[qrow * 200 + h * 16 + 8]);
                #pragma unroll
                for (int d = 0; d < 8; ++d) {
                    qv[d]     = bf2f((unsigned short)qa[d]);
                    qv[d + 8] = bf2f((unsigned short)qb[d]);
                }
            }
            float sc[8], mx = -1e30f;
            #pragma unroll
            for (int b2 = 0; b2 < 8; ++b2) {
                bf16x8 ka = FRAG(&s_qkv[(n2 * 8 + b2) * 200 + 64 + h * 16]);
                bf16x8 kb = FRAG(&s_qkv[(n2 * 8 + b2) * 200 + 64 + h * 16 + 8]);
                float s = 0.f;
                #pragma unroll
                for (int d = 0; d < 8; ++d)
                    s += qv[d] * bf2f((unsigned short)ka[d])
                       + qv[d + 8] * bf2f((unsigned short)kb[d]);
                sc[b2] = s * 0.25f;
                mx = fmaxf(mx, sc[b2]);
            }
            float sum = 0.f;
            #pragma unroll
            for (int b2 = 0; b2 < 8; ++b2) { sc[b2] = __expf(sc[b2] - mx); sum += sc[b2]; }
            float inv = 1.f / sum;
            #pragma unroll
            for (int b2 = 0; b2 < 8; ++b2) s_p[n2][h][a][b2] = sc[b2] * inv;
        } else {
            int t2 = t - 128;
            int n2 = t2 >> 5, b2 = (t2 >> 2) & 7, h = t2 & 3;
            bf16x8 va = FRAG(&s_qkv[(n2 * 8 + b2) * 200 + 128 + h * 16]);
            bf16x8 vb = FRAG(&s_qkv[(n2 * 8 + b2) * 200 + 128 + h * 16 + 8]);
            float s = 0.f;
            #pragma unroll
            for (int d = 0; d < 8; ++d)
                s += bf2f((unsigned short)va[d]) * s_weff[h * 16 + d]
                   + bf2f((unsigned short)vb[d]) * s_weff[h * 16 + 8 + d];
            s_vw[n2][b2][h] = s;
        }
        __syncthreads();                       // B_c
        if (t < 32) {
            int n2 = t >> 3, a = t & 7;
            float s = s_catt;
            #pragma unroll
            for (int h = 0; h < 4; ++h)
                #pragma unroll
                for (int b2 = 0; b2 < 8; ++b2)
                    s += s_p[n2][h][a][b2] * s_vw[n2][b2][h];
            attended[R0 + t] = s;
        }
    }
}

// ===========================================================================
// K2a v2: hypernet layer-1. 256 blocks x 64 rows, 512 threads (8 waves).
// A full-K in LDS; Wcat streamed in K=64 chunks via LDS.
// ===========================================================================
__global__ __launch_bounds__(512, 2) void k_hyp1(
    const float* __restrict__ states,
    const float* __restrict__ bh1a, const float* __restrict__ bhfa,
    const float* __restrict__ bv1,  const float* __restrict__ bb1,
    const float* __restrict__ Wv2,
    const unsigned char* __restrict__ ws_w, unsigned char* __restrict__ ws_o)
{
    __shared__ __align__(16) unsigned short s_st[64 * 520];   // 66.56 KB
    __shared__ __align__(16) unsigned short s_b[640 * 72];    // 92.16 KB

    const int t = threadIdx.x;
    const int w = t >> 6, lane = t & 63, m = lane & 15, q = lane >> 4;
    const int rt = w & 3, ch = w >> 2;
    const int n0 = blockIdx.x * 64;

    const unsigned short* wcat = (const unsigned short*)(ws_w + WCAT_OFF);
    unsigned short* h1a_ws = (unsigned short*)(ws_o + H1A_OFF);
    unsigned short* hfa_ws = (unsigned short*)(ws_o + HFA_OFF);
    unsigned short* b1_ws  = (unsigned short*)(ws_o + B1_OFF);
    float* vsum_ws = (float*)(ws_o + VSUM_OFF);

    // stage A: states fp32 -> bf16 [64][520]
    #pragma unroll
    for (int c = 0; c < 8; ++c) {
        int i = t + c * 512, row = i >> 6, x8 = i & 63;
        const float* sp = states + (size_t)(n0 + row) * 512 + x8 * 8;
        float4 f0 = *(const float4*)sp, f1 = *(const float4*)(sp + 4);
        bf16x8 h;
        h[0]=(short)f2bf(f0.x); h[1]=(short)f2bf(f0.y); h[2]=(short)f2bf(f0.z); h[3]=(short)f2bf(f0.w);
        h[4]=(short)f2bf(f1.x); h[5]=(short)f2bf(f1.y); h[6]=(short)f2bf(f1.z); h[7]=(short)f2bf(f1.w);
        *(bf16x8*)&s_st[row * 520 + x8 * 8] = h;
    }

    f32x4 acc[20];
    #pragma unroll
    for (int i = 0; i < 20; ++i) acc[i] = (f32x4){0.f,0.f,0.f,0.f};

    for (int s = 0; s < 8; ++s) {
        __syncthreads();
        #pragma unroll
        for (int c = 0; c < 10; ++c) {         // stage B chunk [640][64]
            int i = t + c * 512, jl = i >> 3, x8 = i & 7;
            *(uint4*)&s_b[jl * 72 + x8 * 8] =
                *(const uint4*)&wcat[(size_t)jl * 520 + s * 64 + x8 * 8];
        }
        __syncthreads();
        #pragma unroll
        for (int kc2 = 0; kc2 < 2; ++kc2) {
            bf16x8 a = FRAG(&s_st[(rt * 16 + m) * 520 + s * 64 + kc2 * 32 + q * 8]);
            #pragma unroll
            for (int ctl = 0; ctl < 20; ++ctl) {
                bf16x8 b = FRAG(&s_b[((ch * 20 + ctl) * 16 + m) * 72 + kc2 * 32 + q * 8]);
                acc[ctl] = MFMA16(a, b, acc[ctl]);
            }
        }
    }
    // fused epilogue
    float vp[4] = {0.f, 0.f, 0.f, 0.f};
    #pragma unroll
    for (int ctl = 0; ctl < 20; ++ctl) {
        int ct = ch * 20 + ctl, jj = ct * 16 + m;
        if (ct < 16) {
            float bb = bh1a[jj];
            #pragma unroll
            for (int r = 0; r < 4; ++r) {
                int row = rt * 16 + q * 4 + r;
                h1a_ws[(size_t)(n0 + row) * 256 + jj] = f2bf(fmaxf(acc[ctl][r] + bb, 0.f));
            }
        } else if (ct < 32) {
            float bb = bhfa[jj - 256];
            #pragma unroll
            for (int r = 0; r < 4; ++r) {
                int row = rt * 16 + q * 4 + r;
                hfa_ws[(size_t)(n0 + row) * 256 + (jj - 256)] = f2bf(fmaxf(acc[ctl][r] + bb, 0.f));
            }
        } else if (ct < 36) {
            float bb = bv1[jj - 512], wv = Wv2[jj - 512];
            #pragma unroll
            for (int r = 0; r < 4; ++r) vp[r] += fmaxf(acc[ctl][r] + bb, 0.f) * wv;
        } else {
            float bb = bb1[jj - 576];
            #pragma unroll
            for (int r = 0; r < 4; ++r) {
                int row = rt * 16 + q * 4 + r;
                b1_ws[(size_t)(n0 + row) * 64 + (jj - 576)] = f2bf(acc[ctl][r] + bb);
            }
        }
    }
    __syncthreads();
    float* s_red = (float*)s_b;
    if (ch == 1) {
        #pragma unroll
        for (int r = 0; r < 4; ++r) s_red[(rt * 16 + q * 4 + r) * 16 + m] = vp[r];
    }
    __syncthreads();
    if (t < 64) {
        float s = 0.f;
        #pragma unroll
        for (int mm = 0; mm < 16; ++mm) s += s_red[t * 16 + mm];
        vsum_ws[n0 + t] = s;
    }
}

// ===========================================================================
// K2b v2: hypernet layer-2 + mix. 256 blocks x 64 rows, 512 threads.
// ===========================================================================
__global__ __launch_bounds__(512, 2) void k_mix(
    const float* __restrict__ bh1b, const float* __restrict__ bhfb,
    const float* __restrict__ bv2,
    const unsigned char* __restrict__ ws, float* __restrict__ out)
{
    __shared__ __align__(16) unsigned short s_A[64 * 264];    // 33.8 KB
    __shared__ __align__(16) unsigned short s_b[512 * 72];    // 73.7 KB
    __shared__ float s_hid[64 * 64];                          // 16 KB
    __shared__ float s_aq[512];

    const int t = threadIdx.x;
    const int w = t >> 6, lane = t & 63, m = lane & 15, q = lane >> 4;
    const int rt = w & 3, ch = w >> 2;
    const int n0 = blockIdx.x * 64;

    const unsigned short* wh1b = (const unsigned short*)(ws + WH1B_OFF);
    const unsigned short* whfb = (const unsigned short*)(ws + WHFB_OFF);
    const float* attended = (const float*)(ws + ATT_OFF);
    const unsigned short* h1a_ws = (const unsigned short*)(ws + H1A_OFF);
    const unsigned short* hfa_ws = (const unsigned short*)(ws + HFA_OFF);
    const unsigned short* b1_ws  = (const unsigned short*)(ws + B1_OFF);
    const float* vsum_ws = (const float*)(ws + VSUM_OFF);

    s_aq[t] = attended[(size_t)n0 * 8 + t];
    #pragma unroll
    for (int c = 0; c < 8; ++c) s_hid[t + c * 512] = 0.f;
    #pragma unroll
    for (int c = 0; c < 4; ++c) {              // stage A <- h1a
        int i = t + c * 512, row = i >> 5, x8 = i & 31;
        *(uint4*)&s_A[row * 264 + x8 * 8] =
            *(const uint4*)&h1a_ws[(size_t)(n0 + row) * 256 + x8 * 8];
    }

    f32x4 acc[16];
    #pragma unroll
    for (int i = 0; i < 16; ++i) acc[i] = (f32x4){0.f,0.f,0.f,0.f};

    for (int s = 0; s < 4; ++s) {
        __syncthreads();
        #pragma unroll
        for (int c = 0; c < 8; ++c) {          // stage Wh1b chunk [512][64]
            int i = t + c * 512, jl = i >> 3, x8 = i & 7;
            *(uint4*)&s_b[jl * 72 + x8 * 8] =
                *(const uint4*)&wh1b[(size_t)jl * 264 + s * 64 + x8 * 8];
        }
        __syncthreads();
        #pragma unroll
        for (int kc2 = 0; kc2 < 2; ++kc2) {
            bf16x8 a = FRAG(&s_A[(rt * 16 + m) * 264 + s * 64 + kc2 * 32 + q * 8]);
            #pragma unroll
            for (int ctl = 0; ctl < 16; ++ctl) {
                bf16x8 b = FRAG(&s_b[((ch * 16 + ctl) * 16 + m) * 72 + kc2 * 32 + q * 8]);
                acc[ctl] = MFMA16(a, b, acc[ctl]);
            }
        }
    }
    // hid partials: hid[row][e] += aq[row][a] * |w1 + b|
    float hp[4][4];
    #pragma unroll
    for (int i = 0; i < 4; ++i)
        #pragma unroll
        for (int r = 0; r < 4; ++r) hp[i][r] = 0.f;
    #pragma unroll
    for (int ctl = 0; ctl < 16; ++ctl) {
        int jj = (ch * 16 + ctl) * 16 + m;
        int ai = jj >> 6, eq = ctl & 3;
        float bb = bh1b[jj];
        #pragma unroll
        for (int r = 0; r < 4; ++r) {
            int row = rt * 16 + q * 4 + r;
            hp[eq][r] += s_aq[row * 8 + ai] * fabsf(acc[ctl][r] + bb);
        }
    }
    __syncthreads();
    #pragma unroll
    for (int eq = 0; eq < 4; ++eq)
        #pragma unroll
        for (int r = 0; r < 4; ++r)
            atomicAdd(&s_hid[(rt * 16 + q * 4 + r) * 64 + eq * 16 + m], hp[eq][r]);
    // restage A <- hfa (different array than s_hid; atomics may still be in flight)
    #pragma unroll
    for (int c = 0; c < 4; ++c) {
        int i = t + c * 512, row = i >> 5, x8 = i & 31;
        *(uint4*)&s_A[row * 264 + x8 * 8] =
            *(const uint4*)&hfa_ws[(size_t)(n0 + row) * 256 + x8 * 8];
    }
    // Whfb fragments straight from global
    bf16x8 wb[2][8];
    #pragma unroll
    for (int c2 = 0; c2 < 2; ++c2)
        #pragma unroll
        for (int kc = 0; kc < 8; ++kc)
            wb[c2][kc] = FRAG(&whfb[((ch * 2 + c2) * 16 + m) * 264 + kc * 32 + q * 8]);
    __syncthreads();
    f32x4 wfacc[2] = { {0.f,0.f,0.f,0.f}, {0.f,0.f,0.f,0.f} };
    #pragma unroll
    for (int kc = 0; kc < 8; ++kc) {
        bf16x8 a = FRAG(&s_A[(rt * 16 + m) * 264 + kc * 32 + q * 8]);
        #pragma unroll
        for (int c2 = 0; c2 < 2; ++c2) wfacc[c2] = MFMA16(a, wb[c2][kc], wfacc[c2]);
    }
    float prt[4] = {0.f, 0.f, 0.f, 0.f};
    #pragma unroll
    for (int c2 = 0; c2 < 2; ++c2) {
        int e = (ch * 2 + c2) * 16 + m;
        float bb = bhfb[e];
        #pragma unroll
        for (int r = 0; r < 4; ++r) {
            int row = rt * 16 + q * 4 + r;
            float wf = fabsf(wfacc[c2][r] + bb);
            float hv = s_hid[row * 64 + e] + bf2f(b1_ws[(size_t)(n0 + row) * 64 + e]);
            hv = (hv > 0.f) ? hv : expm1f(hv);
            prt[r] += wf * hv;
        }
    }
    __syncthreads();
    float* s_red = (float*)s_b;
    #pragma unroll
    for (int r = 0; r < 4; ++r)
        s_red[(rt * 16 + q * 4 + r) * 32 + ch * 16 + m] = prt[r];
    __syncthreads();
    if (t < 64) {
        float y = bv2[0] + vsum_ws[n0 + t];
        #pragma unroll
        for (int i = 0; i < 32; ++i) y += s_red[t * 32 + i];
        out[n0 + t] = y;
    }
}

// ===========================================================================
// Fallback (round-1, validated) kernels — used if ws_size is too small.
// ===========================================================================
#define NBF 16
__global__ __launch_bounds__(256) void k_enc_attn_fb(
    const float* __restrict__ agent_qs, const float* __restrict__ observations,
    const int* __restrict__ actions,
    const float* __restrict__ W_obs, const float* __restrict__ b_obs,
    const float* __restrict__ W_act, const float* __restrict__ b_act,
    const float* __restrict__ W_q,   const float* __restrict__ b_q,
    const float* __restrict__ Wqkv,  const float* __restrict__ bqkv,
    const float* __restrict__ Wo,    const float* __restrict__ bo,
    const float* __restrict__ Wa2q,  const float* __restrict__ ba2q,
    float* __restrict__ attended)
{
    __shared__ __align__(16) float s_obs[AG][OBSD];
    __shared__ __align__(16) float s_x[AG][ED];
    __shared__ __align__(16) float s_qkv[AG][3*ED];
    __shared__ float s_p[4][AG][AG];
    __shared__ __align__(16) float s_o[AG][ED];
    const int n = blockIdx.x, t = threadIdx.x;
    { const float4* g = (const float4*)(observations + (size_t)n*(AG*OBSD));
      float4* s4 = (float4*)&s_obs[0][0];
      for (int i = 0; i < 2; ++i) s4[t + i*256] = g[t + i*256]; }
    __syncthreads();
    { const int e = t & 63, a0 = t >> 6;
      const float wq = W_q[e]; const float bias0 = b_obs[e]+b_act[e]+b_q[e];
      const float* wrow = W_obs + e*OBSD;
      for (int g = 0; g < 2; ++g) { const int a = a0 + g*4; float acc = 0.f;
        for (int k = 0; k < OBSD; k += 4) { const float4 wv = *(const float4*)(wrow+k);
          acc += wv.x*s_obs[a][k]+wv.y*s_obs[a][k+1]+wv.z*s_obs[a][k+2]+wv.w*s_obs[a][k+3]; }
        s_x[a][e] = acc + bias0 + W_act[e*NACT + actions[n*AG+a]] + agent_qs[n*AG+a]*wq; } }
    __syncthreads();
    for (int g = 0; g < 6; ++g) { const int i = t + g*256, a = i/192, j = i - a*192;
      const float* wrow = Wqkv + j*ED; float acc = bqkv[j];
      for (int k = 0; k < ED; k += 4) { const float4 wv = *(const float4*)(wrow+k);
        acc += wv.x*s_x[a][k]+wv.y*s_x[a][k+1]+wv.z*s_x[a][k+2]+wv.w*s_x[a][k+3]; }
      s_qkv[a][j] = acc; }
    __syncthreads();
    { const int h = t>>6, a = (t>>3)&7, b = t&7; float acc = 0.f;
      for (int d = 0; d < 16; ++d) acc += s_qkv[a][h*16+d]*s_qkv[b][64+h*16+d];
      s_p[h][a][b] = acc*0.25f; }
    __syncthreads();
    if (t < 32) { const int h = t>>3, a = t&7; float mm = -1e30f;
      for (int b = 0; b < 8; ++b) mm = fmaxf(mm, s_p[h][a][b]);
      float ex[8], sum = 0.f;
      for (int b = 0; b < 8; ++b) { ex[b] = __expf(s_p[h][a][b]-mm); sum += ex[b]; }
      for (int b = 0; b < 8; ++b) s_p[h][a][b] = ex[b]/sum; }
    __syncthreads();
    for (int g = 0; g < 2; ++g) { const int i = t+g*256, a = i>>6, c = i&63, h = c>>4;
      float acc = 0.f;
      for (int b = 0; b < 8; ++b) acc += s_p[h][a][b]*s_qkv[b][128+c];
      s_o[a][c] = acc; }
    __syncthreads();
    for (int g = 0; g < 2; ++g) { const int i = t+g*256, a = i>>6, e2 = i&63;
      const float* wrow = Wo + e2*ED; float acc = bo[e2];
      for (int k = 0; k < ED; k += 4) { const float4 wv = *(const float4*)(wrow+k);
        acc += wv.x*s_o[a][k]+wv.y*s_o[a][k+1]+wv.z*s_o[a][k+2]+wv.w*s_o[a][k+3]; }
      s_x[a][e2] = acc * Wa2q[e2]; }
    __syncthreads();
    if (t < 8) { float s = ba2q[0];
      for (int e2 = 0; e2 < 64; ++e2) s += s_x[t][e2];
      attended[n*AG+t] = s; }
}

__global__ __launch_bounds__(256) void k_mixer_fb(
    const float* __restrict__ states, const float* __restrict__ attended,
    const float* __restrict__ Wh1a, const float* __restrict__ bh1a,
    const float* __restrict__ Wh1b, const float* __restrict__ bh1b,
    const float* __restrict__ Whfa, const float* __restrict__ bhfa,
    const float* __restrict__ Whfb, const float* __restrict__ bhfb,
    const float* __restrict__ Wb1,  const float* __restrict__ bb1,
    const float* __restrict__ Wv1,  const float* __restrict__ bv1,
    const float* __restrict__ Wv2,  const float* __restrict__ bv2,
    float* __restrict__ out)
{
    __shared__ __align__(16) float s_st[NBF][SD];
    __shared__ __align__(16) float s_h[NBF][HYP];
    __shared__ __align__(16) float s_hid[NBF][ED];
    __shared__ __align__(16) float s_prod[NBF][ED];
    __shared__ __align__(16) float s_v[NBF][ED];
    __shared__ float s_aq[NBF][AG];
    const int n0 = blockIdx.x * NBF, t = threadIdx.x;
    { const float4* g = (const float4*)(states + (size_t)n0*SD);
      float4* s4 = (float4*)&s_st[0][0];
      for (int i = 0; i < 8; ++i) s4[t + i*256] = g[t + i*256];
      if (t < NBF*AG) ((float*)s_aq)[t] = attended[n0*AG + t]; }
    __syncthreads();
    { const float* wrow = Wh1a + t*SD; float acc[NBF];
      for (int n = 0; n < NBF; ++n) acc[n] = 0.f;
      for (int k = 0; k < SD; k += 4) { const float4 wv = *(const float4*)(wrow+k);
        for (int n = 0; n < NBF; ++n) { const float4 x = *(const float4*)(&s_st[n][k]);
          acc[n] += wv.x*x.x+wv.y*x.y+wv.z*x.z+wv.w*x.w; } }
      const float bb = bh1a[t];
      for (int n = 0; n < NBF; ++n) s_h[n][t] = fmaxf(acc[n]+bb, 0.f); }
    for (int g = 0; g < 4; ++g) { const int i = t+g*256, n = i>>6, e = i&63;
      const float* wrow = Wb1 + e*SD; float acc = bb1[e];
      for (int k = 0; k < SD; k += 4) { const float4 wv = *(const float4*)(wrow+k);
        const float4 x = *(const float4*)(&s_st[n][k]);
        acc += wv.x*x.x+wv.y*x.y+wv.z*x.z+wv.w*x.w; }
      s_hid[n][e] = acc; }
    __syncthreads();
    for (int g = 0; g < 2; ++g) { const int j = t+g*256;
      const float* wrow = Wh1b + j*HYP; float acc[NBF];
      for (int n = 0; n < NBF; ++n) acc[n] = 0.f;
      for (int k = 0; k < HYP; k += 4) { const float4 wv = *(const float4*)(wrow+k);
        for (int n = 0; n < NBF; ++n) { const float4 x = *(const float4*)(&s_h[n][k]);
          acc[n] += wv.x*x.x+wv.y*x.y+wv.z*x.z+wv.w*x.w; } }
      const float bb = bh1b[j]; const int a = j>>6, e = j&63;
      for (int n = 0; n < NBF; ++n)
        atomicAdd(&s_hid[n][e], s_aq[n][a]*fabsf(acc[n]+bb)); }
    __syncthreads();
    { const float* wrow = Whfa + t*SD; float acc[NBF];
      for (int n = 0; n < NBF; ++n) acc[n] = 0.f;
      for (int k = 0; k < SD; k += 4) { const float4 wv = *(const float4*)(wrow+k);
        for (int n = 0; n < NBF; ++n) { const float4 x = *(const float4*)(&s_st[n][k]);
          acc[n] += wv.x*x.x+wv.y*x.y+wv.z*x.z+wv.w*x.w; } }
      const float bb = bhfa[t];
      for (int n = 0; n < NBF; ++n) s_h[n][t] = fmaxf(acc[n]+bb, 0.f); }
    __syncthreads();
    for (int g = 0; g < 4; ++g) { const int i = t+g*256, n = i>>6, e = i&63;
      { const float* wrow = Whfb + e*HYP; float acc = bhfb[e];
        for (int k = 0; k < HYP; k += 4) { const float4 wv = *(const float4*)(wrow+k);
          const float4 x = *(const float4*)(&s_h[n][k]);
          acc += wv.x*x.x+wv.y*x.y+wv.z*x.z+wv.w*x.w; }
        float h = s_hid[n][e]; h = (h > 0.f) ? h : expm1f(h);
        s_prod[n][e] = fabsf(acc)*h; }
      { const float* wrow = Wv1 + e*SD; float acc = bv1[e];
        for (int k = 0; k < SD; k += 4) { const float4 wv = *(const float4*)(wrow+k);
          const float4 x = *(const float4*)(&s_st[n][k]);
          acc += wv.x*x.x+wv.y*x.y+wv.z*x.z+wv.w*x.w; }
        s_v[n][e] = fmaxf(acc, 0.f)*Wv2[e]; } }
    __syncthreads();
    if (t < NBF) { float y = bv2[0];
      for (int e = 0; e < ED; ++e) y += s_prod[t][e] + s_v[t][e];
      out[n0+t] = y; }
}

// ===========================================================================
extern "C" void kernel_launch(void* const* d_in, const int* in_sizes, int n_in,
                              void* d_out, int out_size, void* d_ws, size_t ws_size,
                              hipStream_t stream) {
    const float* agent_qs     = (const float*)d_in[0];
    const float* states       = (const float*)d_in[1];
    const float* observations = (const float*)d_in[2];
    const int*   actions      = (const int*)  d_in[3];
    const float* W_obs = (const float*)d_in[4];  const float* b_obs = (const float*)d_in[5];
    const float* W_act = (const float*)d_in[6];  const float* b_act = (const float*)d_in[7];
    const float* W_q   = (const float*)d_in[8];  const float* b_q   = (const float*)d_in[9];
    const float* Wqkv  = (const float*)d_in[10]; const float* bqkv  = (const float*)d_in[11];
    const float* Wo    = (const float*)d_in[12]; const float* bo    = (const float*)d_in[13];
    const float* Wa2q  = (const float*)d_in[14]; const float* ba2q  = (const float*)d_in[15];
    const float* Wh1a  = (const float*)d_in[16]; const float* bh1a  = (const float*)d_in[17];
    const float* Wh1b  = (const float*)d_in[18]; const float* bh1b  = (const float*)d_in[19];
    const float* Whfa  = (const float*)d_in[20]; const float* bhfa  = (const float*)d_in[21];
    const float* Whfb  = (const float*)d_in[22]; const float* bhfb  = (const float*)d_in[23];
    const float* Wb1   = (const float*)d_in[24]; const float* bb1   = (const float*)d_in[25];
    const float* Wv1   = (const float*)d_in[26]; const float* bv1   = (const float*)d_in[27];
    const float* Wv2   = (const float*)d_in[28]; const float* bv2   = (const float*)d_in[29];
    float* out = (float*)d_out;

    if (ws_size >= WS_NEED) {
        unsigned char* ws = (unsigned char*)d_ws;
        float* attended = (float*)(ws + ATT_OFF);
        k_prep<<<512, 256, 0, stream>>>(W_obs, W_act, W_q, b_obs, b_act, b_q,
                                        Wqkv, bqkv, Wo, bo, Wa2q, ba2q,
                                        Wh1a, Whfa, Wv1, Wb1, Wh1b, Whfb, ws);
        k_enc<<<512, 256, 0, stream>>>(agent_qs, observations, actions, ws, attended);
        k_hyp1<<<N_TOT / 64, 512, 0, stream>>>(states, bh1a, bhfa, bv1, bb1, Wv2,
                                               ws, ws);
        k_mix<<<N_TOT / 64, 512, 0, stream>>>(bh1b, bhfb, bv2, ws, out);
    } else {
        float* attended = (float*)d_ws;
        k_enc_attn_fb<<<N_TOT, 256, 0, stream>>>(agent_qs, observations, actions,
            W_obs, b_obs, W_act, b_act, W_q, b_q, Wqkv, bqkv, Wo, bo, Wa2q, ba2q, attended);
        k_mixer_fb<<<N_TOT / NBF, 256, 0, stream>>>(states, attended,
            Wh1a, bh1a, Wh1b, bh1b, Whfa, bhfa, Whfb, bhfb,
            Wb1, bb1, Wv1, bv1, Wv2, bv2, out);
    }
}